// Round 12
// baseline (40.041 us; speedup 1.0000x reference)
//
#include <hip/hip_runtime.h>

// GraphSearchPolicy, two-kernel MFMA formulation, BB=4, 256-thr blocks,
// 4 independent blocks/CU. MI355X gfx950.
// B=2048, A=256, DE=128, DH=256, DR=128, DIN=512, ACT=256, NR=1000.
//
// prep_kernel: packs W1/W2/rel_emb^T into bf16 MFMA B-fragment tiles (d_ws).
// policy_kernel (grid 512 x 256 thr, ~31 KB LDS -> 4 blocks/CU = 16 waves/CU
// in 4 independently-barriered streams; each wave owns 4x the n-tiles of R10,
// giving 4 independent accumulator chains for MFMA-latency hiding):
//   L1: [4x512]@[512x256] -> h    L2: [4x256]@[256x128] -> x2
//   SC: [4x128]@[128x1008] -> score   then wave-local softmax+entropy.
// A-operand hi/lo split packed into M rows: rows 0-3 = bf16-hi of batch rows,
// rows 4-7 = bf16-residual; one MFMA per (kt,ntile); true row r = C[r]+C[r+4]
// via shfl_xor(.,16) (C mapping HW-verified: col=lane&15, row=(lane>>4)*4+reg).

#define DE   128
#define DH   256
#define DR   128
#define DIN  512
#define ACT  256
#define AA   256
#define BB   4
#define NR   1000
#define SCL  1008            // padded score width (63 n-tiles)

#define XS_P 520             // xs row stride (floats)
#define HS_P 264             // hs row stride
#define X2_P 136             // x2 row stride

#define W2B_OFF 16384        // uint4 offsets into d_ws
#define RB_OFF  20480
#define PREP_T  36608        // 572 tiles * 64 lanes

typedef __attribute__((ext_vector_type(4))) float f32x4;
typedef __attribute__((ext_vector_type(8))) short s16x8;
typedef unsigned int u32;

#define MFMA(a,b,c) __builtin_amdgcn_mfma_f32_16x16x32_bf16(a, b, c, 0, 0, 0)

__device__ __forceinline__ u32 b16(float x) {            // fp32 -> bf16 (RNE)
    u32 u = __float_as_uint(x);
    return (u + 0x7FFFu + ((u >> 16) & 1u)) >> 16;
}
__device__ __forceinline__ float b16f(u32 h) { return __uint_as_float(h << 16); }
__device__ __forceinline__ u32 pack2(float a, float b) { return b16(a) | (b16(b) << 16); }

__device__ __forceinline__ s16x8 asfrag(uint4 v) {
    union { uint4 u; s16x8 s; } c; c.u = v; return c.s;
}

// 8 consecutive fp32 -> ONE bf16 fragment: hi part if !lo, residual if lo.
__device__ __forceinline__ uint4 build_one(const float* p, bool lo) {
    const float4 a = *(const float4*)p;
    const float4 b = *(const float4*)(p + 4);
    const float f[8] = {a.x, a.y, a.z, a.w, b.x, b.y, b.z, b.w};
    u32 o[8];
    #pragma unroll
    for (int i = 0; i < 8; ++i) {
        const u32  h = b16(f[i]);
        const float r = f[i] - b16f(h);
        o[i] = lo ? b16(r) : h;
    }
    uint4 v;
    v.x = o[0] | (o[1] << 16); v.y = o[2] | (o[3] << 16);
    v.z = o[4] | (o[5] << 16); v.w = o[6] | (o[7] << 16);
    return v;
}

// ---------------------------------------------------------------- prep
// B-fragment tiles: value reg v of lane l in tile (kt,nt) covers
// n = nt*16 + (l&15), k = kt*32 + (l>>4)*8 + {2v, 2v+1}.
__global__ __launch_bounds__(256) void prep_kernel(
    const float* __restrict__ W1, const float* __restrict__ W2,
    const float* __restrict__ rel_emb, uint4* __restrict__ wsb)
{
    const int id = blockIdx.x * 256 + threadIdx.x;       // 0..36607
    const int l  = id & 63;
    const int tl = id >> 6;                              // tile 0..571
    const int kb_l = (l >> 4) * 8;
    const int n_l  = l & 15;
    float f[8];
    if (tl < 256) {                                      // W1B: tl = kt*16+nt
        const int kt = tl >> 4, nt = tl & 15;
        const int kb = kt * 32 + kb_l, n = nt * 16 + n_l;
        #pragma unroll
        for (int i = 0; i < 8; ++i) f[i] = W1[(size_t)(kb + i) * ACT + n];
    } else if (tl < 320) {                               // W2B: tl-256 = kt*8+nt
        const int t2 = tl - 256;
        const int kt = t2 >> 3, nt = t2 & 7;
        const int kb = kt * 32 + kb_l, n = nt * 16 + n_l;
        #pragma unroll
        for (int i = 0; i < 8; ++i) f[i] = W2[(size_t)(kb + i) * DR + n];
    } else {                                             // RB: tl-320 = nt*4+kt
        const int t3 = tl - 320;                         // 0..251
        const int nt = t3 >> 2, kt = t3 & 3;
        const int kb = kt * 32 + kb_l, n = nt * 16 + n_l;
        #pragma unroll
        for (int i = 0; i < 8; ++i)
            f[i] = (n < NR) ? rel_emb[(size_t)n * DR + kb + i] : 0.f;
    }
    uint4 o;
    o.x = pack2(f[0], f[1]); o.y = pack2(f[2], f[3]);
    o.z = pack2(f[4], f[5]); o.w = pack2(f[6], f[7]);
    wsb[id] = o;
}

// ---------------------------------------------------------------- main
__global__ __launch_bounds__(256, 4) void policy_kernel(
    const int*   __restrict__ e,
    const int*   __restrict__ q,
    const float* __restrict__ H,
    const int*   __restrict__ r_space,
    const float* __restrict__ r_mask,
    const float* __restrict__ entity_emb,
    const float* __restrict__ rel_emb,
    const float* __restrict__ b1,
    const float* __restrict__ b2,
    const uint4* __restrict__ wsb,
    float* __restrict__ dist_out,
    float* __restrict__ ent_out)
{
    const int t  = threadIdx.x;          // 0..255
    const int b0 = blockIdx.x * BB;
    const int l  = t & 63;
    const int w  = t >> 6;               // wave 0..3
    const int m  = l & 15;               // fragment row slot
    const bool mval = (m < 8);           // rows 0-3 hi, 4-7 lo, 8-15 zero
    const int  arow = m & 3;
    const bool lo   = (m & 4) != 0;
    const int kb_l  = (l >> 4) * 8;

    __shared__ __align__(16) float xs[BB * XS_P];    //  8.3 KB
    __shared__ __align__(16) float hs[BB * HS_P];    //  4.2 KB
    __shared__ __align__(16) float x2s[BB * X2_P];   //  2.2 KB
    __shared__ float scoreL[BB * SCL];               // 16.1 KB

    // ---- early loads: wave w owns batch row w; 4 actions/lane ----
    int   ridx[4];
    float msk [4];
    #pragma unroll
    for (int c = 0; c < 4; ++c) {
        ridx[c] = r_space[(size_t)(b0 + w) * AA + l + 64 * c];
        msk [c] = r_mask [(size_t)(b0 + w) * AA + l + 64 * c];
    }

    // ---- stage X = concat(E,H,Q): 2 float4/thread ----
    #pragma unroll
    for (int u = 0; u < 2; ++u) {
        const int j   = t + u * 256;     // 0..511
        const int row = j >> 7;          // 0..3
        const int k   = (j & 127) * 4;   // 0..508
        const int sb  = b0 + row;
        float4 v;
        if (k < DE)            v = *(const float4*)&entity_emb[(size_t)e[sb] * DE + k];
        else if (k < DE + DH)  v = *(const float4*)&H[(size_t)sb * DH + (k - DE)];
        else                   v = *(const float4*)&rel_emb[(size_t)q[sb] * DR + (k - DE - DH)];
        *(float4*)&xs[row * XS_P + k] = v;
    }
    __syncthreads();

    // ================= layer 1: wave owns n-tiles {4w .. 4w+3} ==============
    {
        f32x4 acc[4] = {{0,0,0,0}, {0,0,0,0}, {0,0,0,0}, {0,0,0,0}};
        const int ntb = 4 * w;
        #pragma unroll 4
        for (int kt = 0; kt < 16; ++kt) {
            uint4 af = {0, 0, 0, 0};
            if (mval) af = build_one(&xs[arow * XS_P + kt * 32 + kb_l], lo);
            #pragma unroll
            for (int ni = 0; ni < 4; ++ni) {
                const uint4 bv = wsb[(size_t)(kt * 16 + ntb + ni) * 64 + l];
                acc[ni] = MFMA(asfrag(af), asfrag(bv), acc[ni]);  // 4 indep chains
            }
        }
        #pragma unroll
        for (int ni = 0; ni < 4; ++ni) {
            #pragma unroll
            for (int v = 0; v < 4; ++v)   // row r (lanes 0-15) += row r+4 (16-31)
                acc[ni][v] += __shfl_xor(acc[ni][v], 16, 64);
        }
        if (l < 16) {                     // lanes 0-15 hold rows v=0..3, col=l
            #pragma unroll
            for (int ni = 0; ni < 4; ++ni) {
                const int n = (ntb + ni) * 16 + l;
                const float bb = b1[n];
                #pragma unroll
                for (int v = 0; v < 4; ++v)
                    hs[v * HS_P + n] = fmaxf(acc[ni][v] + bb, 0.f);
            }
        }
    }
    __syncthreads();

    // ================= layer 2: wave owns n-tiles {2w, 2w+1} ================
    {
        f32x4 acc0 = {0.f, 0.f, 0.f, 0.f};
        f32x4 acc1 = {0.f, 0.f, 0.f, 0.f};
        const int nt0 = 2 * w, nt1 = 2 * w + 1;
        #pragma unroll 4
        for (int kt = 0; kt < 8; ++kt) {
            uint4 af = {0, 0, 0, 0};
            if (mval) af = build_one(&hs[arow * HS_P + kt * 32 + kb_l], lo);
            const uint4 bv0 = wsb[(size_t)(W2B_OFF + (kt * 8 + nt0) * 64 + l)];
            const uint4 bv1 = wsb[(size_t)(W2B_OFF + (kt * 8 + nt1) * 64 + l)];
            acc0 = MFMA(asfrag(af), asfrag(bv0), acc0);
            acc1 = MFMA(asfrag(af), asfrag(bv1), acc1);
        }
        #pragma unroll
        for (int v = 0; v < 4; ++v) {
            acc0[v] += __shfl_xor(acc0[v], 16, 64);
            acc1[v] += __shfl_xor(acc1[v], 16, 64);
        }
        if (l < 16) {
            const int n0 = nt0 * 16 + l, n1 = nt1 * 16 + l;
            const float bb0 = b2[n0], bb1 = b2[n1];
            #pragma unroll
            for (int v = 0; v < 4; ++v) {
                x2s[v * X2_P + n0] = acc0[v] + bb0;
                x2s[v * X2_P + n1] = acc1[v] + bb1;
            }
        }
    }
    __syncthreads();

    // ================= score: wave owns up to 16 n-tiles ====================
    {
        uint4 sf[4] = {{0,0,0,0}, {0,0,0,0}, {0,0,0,0}, {0,0,0,0}};
        #pragma unroll
        for (int kt = 0; kt < 4; ++kt)
            if (mval) sf[kt] = build_one(&x2s[arow * X2_P + kt * 32 + kb_l], lo);
        #pragma unroll 2
        for (int i = 0; i < 16; ++i) {
            const int nt = 16 * w + i;
            if (nt >= 63) break;          // wave 3: 15 tiles (uniform branch)
            f32x4 acc = {0.f, 0.f, 0.f, 0.f};
            #pragma unroll
            for (int kt = 0; kt < 4; ++kt) {
                const uint4 bv = wsb[(size_t)(RB_OFF + (nt * 4 + kt) * 64 + l)];
                acc = MFMA(asfrag(sf[kt]), asfrag(bv), acc);
            }
            #pragma unroll
            for (int v = 0; v < 4; ++v) acc[v] += __shfl_xor(acc[v], 16, 64);
            if (l < 16) {
                const int n = nt * 16 + l;
                #pragma unroll
                for (int v = 0; v < 4; ++v)
                    scoreL[v * SCL + n] = acc[v];
            }
        }
    }
    __syncthreads();

    // ================= wave-local softmax + entropy (wave w = row w) ========
    {
        float lg[4];
        #pragma unroll
        for (int c = 0; c < 4; ++c)
            lg[c] = scoreL[w * SCL + ridx[c]] - (1.0f - msk[c]) * 1e31f;

        float mx = fmaxf(fmaxf(lg[0], lg[1]), fmaxf(lg[2], lg[3]));
        #pragma unroll
        for (int off = 32; off >= 1; off >>= 1)
            mx = fmaxf(mx, __shfl_xor(mx, off, 64));

        float p[4], S = 0.f, SLacc = 0.f;
        #pragma unroll
        for (int c = 0; c < 4; ++c) {
            const float z = lg[c] - mx;
            p[c] = __expf(z);
            S    += p[c];
            SLacc += p[c] * z;
        }
        #pragma unroll
        for (int off = 32; off >= 1; off >>= 1) {
            S     += __shfl_xor(S,     off, 64);
            SLacc += __shfl_xor(SLacc, off, 64);
        }

        const float inv = 1.0f / S;
        #pragma unroll
        for (int c = 0; c < 4; ++c)
            dist_out[(size_t)(b0 + w) * AA + l + 64 * c] = p[c] * inv;
        if (l == 0)
            ent_out[b0 + w] = __logf(S) - SLacc * inv;
    }
}

extern "C" void kernel_launch(void* const* d_in, const int* in_sizes, int n_in,
                              void* d_out, int out_size, void* d_ws, size_t ws_size,
                              hipStream_t stream) {
    const int*   e          = (const int*)  d_in[0];
    const int*   q          = (const int*)  d_in[1];
    const float* H          = (const float*)d_in[2];
    const int*   r_space    = (const int*)  d_in[3];
    const float* r_mask     = (const float*)d_in[4];
    const float* entity_emb = (const float*)d_in[5];
    const float* rel_emb    = (const float*)d_in[6];
    const float* W1         = (const float*)d_in[7];
    const float* b1         = (const float*)d_in[8];
    const float* W2         = (const float*)d_in[9];
    const float* b2         = (const float*)d_in[10];

    const int B = in_sizes[0];              // 2048
    float* dist_out = (float*)d_out;                    // [B, 256]
    float* ent_out  = (float*)d_out + (size_t)B * AA;   // [B]
    uint4* wsb      = (uint4*)d_ws;                     // 572 KB packed B-frags

    prep_kernel<<<PREP_T / 256, 256, 0, stream>>>(W1, W2, rel_emb, wsb);
    policy_kernel<<<B / BB, 256, 0, stream>>>(
        e, q, H, r_space, r_mask, entity_emb, rel_emb,
        b1, b2, wsb, dist_out, ent_out);
}

// Round 13
// 22.679 us; speedup vs baseline: 1.7656x; 1.7656x over previous
//
#include <hip/hip_runtime.h>

// GraphSearchPolicy, two-kernel MFMA, BB=8, bf16 hi/lo planes in LDS.
// MI355X gfx950. B=2048, A=256, DE=128, DH=256, DR=128, DIN=512, ACT=256, NR=1000.
//
// prep_kernel: packs W1/W2/rel_emb^T into bf16 MFMA B-fragment tiles (d_ws).
// policy_kernel (grid 256 x 512 thr, ~62 KB LDS -> 2 blocks/CU):
// X/h/x2 live in LDS as bf16 hi/lo PLANES so the MFMA A-fragment is ONE
// ds_read_b128 (no per-K-step conversion VALU in the dependency chain).
// M-packing: rows 0-7 = hi(batch rows 0-7), rows 8-15 = lo residuals; one
// MFMA per (kt,ntile); true row r = C[r] + C[r+8] via shfl_xor(.,32).
// C mapping (HW-verified): col = lane&15, row = (lane>>4)*4 + reg.

#define DE   128
#define DH   256
#define DR   128
#define DIN  512
#define ACT  256
#define AA   256
#define BB   8
#define NR   1000
#define SCL  1008            // padded score width (63 n-tiles)

#define XS_P 520             // bf16-plane row strides (elements)
#define HS_P 264
#define X2_P 136

#define W2B_OFF 16384        // uint4 offsets into d_ws
#define RB_OFF  20480
#define PREP_T  36608        // 572 tiles * 64 lanes

typedef __attribute__((ext_vector_type(4))) float f32x4;
typedef __attribute__((ext_vector_type(8))) short s16x8;
typedef unsigned int u32;
typedef unsigned short u16;

#define MFMA(a,b,c) __builtin_amdgcn_mfma_f32_16x16x32_bf16(a, b, c, 0, 0, 0)

__device__ __forceinline__ u32 b16(float x) {            // fp32 -> bf16 (RNE)
    u32 u = __float_as_uint(x);
    return (u + 0x7FFFu + ((u >> 16) & 1u)) >> 16;
}
__device__ __forceinline__ float b16f(u32 h) { return __uint_as_float(h << 16); }
__device__ __forceinline__ u32 pack2(float a, float b) { return b16(a) | (b16(b) << 16); }

__device__ __forceinline__ s16x8 asfrag(uint4 v) {
    union { uint4 u; s16x8 s; } c; c.u = v; return c.s;
}

// ---------------------------------------------------------------- prep
// B-fragment tiles: value reg v of lane l in tile (kt,nt) covers
// n = nt*16 + (l&15), k = kt*32 + (l>>4)*8 + {2v, 2v+1}.
__global__ __launch_bounds__(256) void prep_kernel(
    const float* __restrict__ W1, const float* __restrict__ W2,
    const float* __restrict__ rel_emb, uint4* __restrict__ wsb)
{
    const int id = blockIdx.x * 256 + threadIdx.x;       // 0..36607
    const int l  = id & 63;
    const int tl = id >> 6;                              // tile 0..571
    const int kb_l = (l >> 4) * 8;
    const int n_l  = l & 15;
    float f[8];
    if (tl < 256) {                                      // W1B: tl = kt*16+nt
        const int kt = tl >> 4, nt = tl & 15;
        const int kb = kt * 32 + kb_l, n = nt * 16 + n_l;
        #pragma unroll
        for (int i = 0; i < 8; ++i) f[i] = W1[(size_t)(kb + i) * ACT + n];
    } else if (tl < 320) {                               // W2B: tl-256 = kt*8+nt
        const int t2 = tl - 256;
        const int kt = t2 >> 3, nt = t2 & 7;
        const int kb = kt * 32 + kb_l, n = nt * 16 + n_l;
        #pragma unroll
        for (int i = 0; i < 8; ++i) f[i] = W2[(size_t)(kb + i) * DR + n];
    } else {                                             // RB: tl-320 = nt*4+kt
        const int t3 = tl - 320;                         // 0..251
        const int nt = t3 >> 2, kt = t3 & 3;
        const int kb = kt * 32 + kb_l, n = nt * 16 + n_l;
        #pragma unroll
        for (int i = 0; i < 8; ++i)
            f[i] = (n < NR) ? rel_emb[(size_t)n * DR + kb + i] : 0.f;
    }
    uint4 o;
    o.x = pack2(f[0], f[1]); o.y = pack2(f[2], f[3]);
    o.z = pack2(f[4], f[5]); o.w = pack2(f[6], f[7]);
    wsb[id] = o;
}

// ---------------------------------------------------------------- main
__global__ __launch_bounds__(512, 2) void policy_kernel(
    const int*   __restrict__ e,
    const int*   __restrict__ q,
    const float* __restrict__ H,
    const int*   __restrict__ r_space,
    const float* __restrict__ r_mask,
    const float* __restrict__ entity_emb,
    const float* __restrict__ rel_emb,
    const float* __restrict__ b1,
    const float* __restrict__ b2,
    const uint4* __restrict__ wsb,
    float* __restrict__ dist_out,
    float* __restrict__ ent_out)
{
    const int t  = threadIdx.x;          // 0..511
    const int b0 = blockIdx.x * BB;
    const int l  = t & 63;
    const int w  = t >> 6;               // wave 0..7
    const int m  = l & 15;               // fragment row slot (all 16 used)
    const int pl = m >> 3;               // 0 = hi plane, 1 = lo plane
    const int rw = m & 7;                // source batch row
    const int kb_l = (l >> 4) * 8;

    __shared__ __align__(16) u16 xbf[2][BB][XS_P];   // 16.6 KB bf16 planes
    __shared__ __align__(16) u16 hbf[2][BB][HS_P];   //  8.4 KB
    __shared__ __align__(16) u16 x2bf[2][BB][X2_P];  //  4.3 KB
    __shared__ float scoreL[BB * SCL];               // 31.5 KB

    // ---- early loads: wave w owns batch row w; 4 actions/lane ----
    int   ridx[4];
    float msk [4];
    #pragma unroll
    for (int c = 0; c < 4; ++c) {
        ridx[c] = r_space[(size_t)(b0 + w) * AA + l + 64 * c];
        msk [c] = r_mask [(size_t)(b0 + w) * AA + l + 64 * c];
    }

    // ---- stage X = concat(E,H,Q), converting to hi/lo bf16 planes ----
    #pragma unroll
    for (int u = 0; u < 2; ++u) {
        const int j   = t + u * 512;     // 0..1023
        const int row = j & 7;
        const int kq  = (j >> 3) * 4;    // 0..508
        const int sb  = b0 + row;
        float4 v;
        if (kq < DE)            v = *(const float4*)&entity_emb[(size_t)e[sb] * DE + kq];
        else if (kq < DE + DH)  v = *(const float4*)&H[(size_t)sb * DH + (kq - DE)];
        else                    v = *(const float4*)&rel_emb[(size_t)q[sb] * DR + (kq - DE - DH)];
        const float f[4] = {v.x, v.y, v.z, v.w};
        u32 hi[4], lo[4];
        #pragma unroll
        for (int i = 0; i < 4; ++i) {
            hi[i] = b16(f[i]);
            lo[i] = b16(f[i] - b16f(hi[i]));
        }
        uint2 ph, plv;
        ph.x  = hi[0] | (hi[1] << 16); ph.y  = hi[2] | (hi[3] << 16);
        plv.x = lo[0] | (lo[1] << 16); plv.y = lo[2] | (lo[3] << 16);
        *(uint2*)&xbf[0][row][kq] = ph;      // 8B writes, ~2-way banks: free
        *(uint2*)&xbf[1][row][kq] = plv;
    }
    __syncthreads();

    // ================= layer 1: wave owns n-tiles {2w, 2w+1} ================
    {
        f32x4 acc0 = {0.f, 0.f, 0.f, 0.f};
        f32x4 acc1 = {0.f, 0.f, 0.f, 0.f};
        const int nt0 = 2 * w, nt1 = 2 * w + 1;
        const u16* abase = &xbf[pl][rw][kb_l];
        #pragma unroll
        for (int kt = 0; kt < 16; ++kt) {
            const uint4 af  = *(const uint4*)(abase + kt * 32);   // ONE ds_read_b128
            const uint4 bv0 = wsb[(size_t)(kt * 16 + nt0) * 64 + l];
            const uint4 bv1 = wsb[(size_t)(kt * 16 + nt1) * 64 + l];
            acc0 = MFMA(asfrag(af), asfrag(bv0), acc0);
            acc1 = MFMA(asfrag(af), asfrag(bv1), acc1);
        }
        #pragma unroll
        for (int v = 0; v < 4; ++v) {    // fold lo rows (8-15) into hi rows (0-7)
            acc0[v] += __shfl_xor(acc0[v], 32, 64);
            acc1[v] += __shfl_xor(acc1[v], 32, 64);
        }
        if (l < 32) {                    // lanes 0-31: rows (l>>4)*4+v, col l&15
            const int r4 = (l >> 4) * 4;
            const int n0 = nt0 * 16 + m, n1 = nt1 * 16 + m;
            const float bb0 = b1[n0], bb1 = b1[n1];
            #pragma unroll
            for (int v = 0; v < 4; ++v) {
                const float h0 = fmaxf(acc0[v] + bb0, 0.f);
                const float h1 = fmaxf(acc1[v] + bb1, 0.f);
                const u32 h0h = b16(h0), h1h = b16(h1);
                hbf[0][r4 + v][n0] = (u16)h0h;
                hbf[1][r4 + v][n0] = (u16)b16(h0 - b16f(h0h));
                hbf[0][r4 + v][n1] = (u16)h1h;
                hbf[1][r4 + v][n1] = (u16)b16(h1 - b16f(h1h));
            }
        }
    }
    __syncthreads();

    // ================= layer 2: wave owns n-tile w ==========================
    {
        f32x4 acc = {0.f, 0.f, 0.f, 0.f};
        const u16* abase = &hbf[pl][rw][kb_l];
        #pragma unroll
        for (int kt = 0; kt < 8; ++kt) {
            const uint4 af = *(const uint4*)(abase + kt * 32);
            const uint4 bv = wsb[(size_t)(W2B_OFF + (kt * 8 + w) * 64 + l)];
            acc = MFMA(asfrag(af), asfrag(bv), acc);
        }
        #pragma unroll
        for (int v = 0; v < 4; ++v) acc[v] += __shfl_xor(acc[v], 32, 64);
        if (l < 32) {
            const int r4 = (l >> 4) * 4;
            const int n  = w * 16 + m;
            const float bb = b2[n];
            #pragma unroll
            for (int v = 0; v < 4; ++v) {
                const float x2 = acc[v] + bb;
                const u32 xh = b16(x2);
                x2bf[0][r4 + v][n] = (u16)xh;
                x2bf[1][r4 + v][n] = (u16)b16(x2 - b16f(xh));
            }
        }
    }
    __syncthreads();

    // ================= score: wave owns 8 n-tiles ===========================
    {
        uint4 sf[4];
        const u16* abase = &x2bf[pl][rw][kb_l];
        #pragma unroll
        for (int kt = 0; kt < 4; ++kt)
            sf[kt] = *(const uint4*)(abase + kt * 32);
        #pragma unroll 2
        for (int i = 0; i < 8; ++i) {
            const int nt = w * 8 + i;
            if (nt >= 63) break;         // wave 7: 7 tiles (uniform branch)
            f32x4 acc = {0.f, 0.f, 0.f, 0.f};
            #pragma unroll
            for (int kt = 0; kt < 4; ++kt) {
                const uint4 bv = wsb[(size_t)(RB_OFF + (nt * 4 + kt) * 64 + l)];
                acc = MFMA(asfrag(sf[kt]), asfrag(bv), acc);
            }
            #pragma unroll
            for (int v = 0; v < 4; ++v) acc[v] += __shfl_xor(acc[v], 32, 64);
            if (l < 32) {
                const int r4 = (l >> 4) * 4;
                const int n  = nt * 16 + m;
                #pragma unroll
                for (int v = 0; v < 4; ++v)
                    scoreL[(r4 + v) * SCL + n] = acc[v];   // 4B stride: conflict-free
            }
        }
    }
    __syncthreads();

    // ================= wave-local softmax + entropy (wave w = row w) ========
    {
        float lg[4];
        #pragma unroll
        for (int c = 0; c < 4; ++c)
            lg[c] = scoreL[w * SCL + ridx[c]] - (1.0f - msk[c]) * 1e31f;

        float mx = fmaxf(fmaxf(lg[0], lg[1]), fmaxf(lg[2], lg[3]));
        #pragma unroll
        for (int off = 32; off >= 1; off >>= 1)
            mx = fmaxf(mx, __shfl_xor(mx, off, 64));

        float p[4], S = 0.f, SLa = 0.f;
        #pragma unroll
        for (int c = 0; c < 4; ++c) {
            const float z = lg[c] - mx;
            p[c] = __expf(z);
            S   += p[c];
            SLa += p[c] * z;
        }
        #pragma unroll
        for (int off = 32; off >= 1; off >>= 1) {
            S   += __shfl_xor(S,   off, 64);
            SLa += __shfl_xor(SLa, off, 64);
        }

        const float inv = 1.0f / S;
        #pragma unroll
        for (int c = 0; c < 4; ++c)
            dist_out[(size_t)(b0 + w) * AA + l + 64 * c] = p[c] * inv;
        if (l == 0)
            ent_out[b0 + w] = __logf(S) - SLa * inv;
    }
}

extern "C" void kernel_launch(void* const* d_in, const int* in_sizes, int n_in,
                              void* d_out, int out_size, void* d_ws, size_t ws_size,
                              hipStream_t stream) {
    const int*   e          = (const int*)  d_in[0];
    const int*   q          = (const int*)  d_in[1];
    const float* H          = (const float*)d_in[2];
    const int*   r_space    = (const int*)  d_in[3];
    const float* r_mask     = (const float*)d_in[4];
    const float* entity_emb = (const float*)d_in[5];
    const float* rel_emb    = (const float*)d_in[6];
    const float* W1         = (const float*)d_in[7];
    const float* b1         = (const float*)d_in[8];
    const float* W2         = (const float*)d_in[9];
    const float* b2         = (const float*)d_in[10];

    const int B = in_sizes[0];              // 2048
    float* dist_out = (float*)d_out;                    // [B, 256]
    float* ent_out  = (float*)d_out + (size_t)B * AA;   // [B]
    uint4* wsb      = (uint4*)d_ws;                     // 572 KB packed B-frags

    prep_kernel<<<PREP_T / 256, 256, 0, stream>>>(W1, W2, rel_emb, wsb);
    policy_kernel<<<B / BB, 512, 0, stream>>>(
        e, q, H, r_space, r_mask, entity_emb, rel_emb,
        b1, b2, wsb, dist_out, ent_out);
}

// Round 14
// 20.077 us; speedup vs baseline: 1.9944x; 1.1296x over previous
//
#include <hip/hip_runtime.h>

// GraphSearchPolicy, two-kernel MFMA, BB=8, bf16 hi/lo planes in LDS,
// 1024-thread policy blocks (16 waves = 4 waves/SIMD). MI355X gfx950.
// B=2048, A=256, DE=128, DH=256, DR=128, DIN=512, ACT=256, NR=1000.
//
// prep_kernel: packs W1/W2/rel_emb^T into bf16 MFMA B-fragment tiles (d_ws).
// policy_kernel (grid 256 x 1024 thr, ~62 KB LDS):
// X/h/x2 live in LDS as bf16 hi/lo PLANES so the MFMA A-fragment is ONE
// ds_read_b128 (no conversion VALU in the K-loop dependency chain -- the
// R12 lever, kept). This round: 16 waves/block for 2x in-phase latency
// hiding (layer1: 1 n-tile/wave; score: 4 n-tiles/wave; layer2+softmax on
// waves 0-7, waves 8-15 pass through barriers).
// M-packing: rows 0-7 = hi(batch rows), 8-15 = lo residuals; one MFMA per
// (kt,ntile); true row r = C[r] + C[r+8] via shfl_xor(.,32).
// C mapping (HW-verified): col = lane&15, row = (lane>>4)*4 + reg.

#define DE   128
#define DH   256
#define DR   128
#define DIN  512
#define ACT  256
#define AA   256
#define BB   8
#define NR   1000
#define SCL  1008            // padded score width (63 n-tiles)

#define XS_P 520             // bf16-plane row strides (elements)
#define HS_P 264
#define X2_P 136

#define W2B_OFF 16384        // uint4 offsets into d_ws
#define RB_OFF  20480
#define PREP_T  36608        // 572 tiles * 64 lanes

typedef __attribute__((ext_vector_type(4))) float f32x4;
typedef __attribute__((ext_vector_type(8))) short s16x8;
typedef unsigned int u32;
typedef unsigned short u16;

#define MFMA(a,b,c) __builtin_amdgcn_mfma_f32_16x16x32_bf16(a, b, c, 0, 0, 0)

__device__ __forceinline__ u32 b16(float x) {            // fp32 -> bf16 (RNE)
    u32 u = __float_as_uint(x);
    return (u + 0x7FFFu + ((u >> 16) & 1u)) >> 16;
}
__device__ __forceinline__ float b16f(u32 h) { return __uint_as_float(h << 16); }
__device__ __forceinline__ u32 pack2(float a, float b) { return b16(a) | (b16(b) << 16); }

__device__ __forceinline__ s16x8 asfrag(uint4 v) {
    union { uint4 u; s16x8 s; } c; c.u = v; return c.s;
}

// ---------------------------------------------------------------- prep
// B-fragment tiles: value reg v of lane l in tile (kt,nt) covers
// n = nt*16 + (l&15), k = kt*32 + (l>>4)*8 + {2v, 2v+1}.
__global__ __launch_bounds__(256) void prep_kernel(
    const float* __restrict__ W1, const float* __restrict__ W2,
    const float* __restrict__ rel_emb, uint4* __restrict__ wsb)
{
    const int id = blockIdx.x * 256 + threadIdx.x;       // 0..36607
    const int l  = id & 63;
    const int tl = id >> 6;                              // tile 0..571
    const int kb_l = (l >> 4) * 8;
    const int n_l  = l & 15;
    float f[8];
    if (tl < 256) {                                      // W1B: tl = kt*16+nt
        const int kt = tl >> 4, nt = tl & 15;
        const int kb = kt * 32 + kb_l, n = nt * 16 + n_l;
        #pragma unroll
        for (int i = 0; i < 8; ++i) f[i] = W1[(size_t)(kb + i) * ACT + n];
    } else if (tl < 320) {                               // W2B: tl-256 = kt*8+nt
        const int t2 = tl - 256;
        const int kt = t2 >> 3, nt = t2 & 7;
        const int kb = kt * 32 + kb_l, n = nt * 16 + n_l;
        #pragma unroll
        for (int i = 0; i < 8; ++i) f[i] = W2[(size_t)(kb + i) * DR + n];
    } else {                                             // RB: tl-320 = nt*4+kt
        const int t3 = tl - 320;                         // 0..251
        const int nt = t3 >> 2, kt = t3 & 3;
        const int kb = kt * 32 + kb_l, n = nt * 16 + n_l;
        #pragma unroll
        for (int i = 0; i < 8; ++i)
            f[i] = (n < NR) ? rel_emb[(size_t)n * DR + kb + i] : 0.f;
    }
    uint4 o;
    o.x = pack2(f[0], f[1]); o.y = pack2(f[2], f[3]);
    o.z = pack2(f[4], f[5]); o.w = pack2(f[6], f[7]);
    wsb[id] = o;
}

// ---------------------------------------------------------------- main
__global__ __launch_bounds__(1024, 2) void policy_kernel(
    const int*   __restrict__ e,
    const int*   __restrict__ q,
    const float* __restrict__ H,
    const int*   __restrict__ r_space,
    const float* __restrict__ r_mask,
    const float* __restrict__ entity_emb,
    const float* __restrict__ rel_emb,
    const float* __restrict__ b1,
    const float* __restrict__ b2,
    const uint4* __restrict__ wsb,
    float* __restrict__ dist_out,
    float* __restrict__ ent_out)
{
    const int t  = threadIdx.x;          // 0..1023
    const int b0 = blockIdx.x * BB;
    const int l  = t & 63;
    const int w  = t >> 6;               // wave 0..15
    const int m  = l & 15;               // fragment row slot (all 16 used)
    const int pl = m >> 3;               // 0 = hi plane, 1 = lo plane
    const int rw = m & 7;                // source batch row
    const int kb_l = (l >> 4) * 8;

    __shared__ __align__(16) u16 xbf[2][BB][XS_P];   // 16.6 KB bf16 planes
    __shared__ __align__(16) u16 hbf[2][BB][HS_P];   //  8.4 KB
    __shared__ __align__(16) u16 x2bf[2][BB][X2_P];  //  4.3 KB
    __shared__ float scoreL[BB * SCL];               // 31.5 KB

    // ---- early loads: waves 0-7 own batch row w; 4 actions/lane ----
    int   ridx[4];
    float msk [4];
    if (w < 8) {
        #pragma unroll
        for (int c = 0; c < 4; ++c) {
            ridx[c] = r_space[(size_t)(b0 + w) * AA + l + 64 * c];
            msk [c] = r_mask [(size_t)(b0 + w) * AA + l + 64 * c];
        }
    }

    // ---- stage X = concat(E,H,Q), converting to hi/lo bf16 planes ----
    {
        const int row = t & 7;
        const int kq  = (t >> 3) * 4;    // 0..508
        const int sb  = b0 + row;
        float4 v;
        if (kq < DE)            v = *(const float4*)&entity_emb[(size_t)e[sb] * DE + kq];
        else if (kq < DE + DH)  v = *(const float4*)&H[(size_t)sb * DH + (kq - DE)];
        else                    v = *(const float4*)&rel_emb[(size_t)q[sb] * DR + (kq - DE - DH)];
        const float f[4] = {v.x, v.y, v.z, v.w};
        u32 hi[4], lo[4];
        #pragma unroll
        for (int i = 0; i < 4; ++i) {
            hi[i] = b16(f[i]);
            lo[i] = b16(f[i] - b16f(hi[i]));
        }
        uint2 ph, plv;
        ph.x  = hi[0] | (hi[1] << 16); ph.y  = hi[2] | (hi[3] << 16);
        plv.x = lo[0] | (lo[1] << 16); plv.y = lo[2] | (lo[3] << 16);
        *(uint2*)&xbf[0][row][kq] = ph;
        *(uint2*)&xbf[1][row][kq] = plv;
    }
    __syncthreads();

    // ================= layer 1: wave owns n-tile w ==========================
    {
        f32x4 acc = {0.f, 0.f, 0.f, 0.f};
        const u16* abase = &xbf[pl][rw][kb_l];
        #pragma unroll
        for (int kt = 0; kt < 16; ++kt) {
            const uint4 af = *(const uint4*)(abase + kt * 32);    // ONE ds_read_b128
            const uint4 bv = wsb[(size_t)(kt * 16 + w) * 64 + l];
            acc = MFMA(asfrag(af), asfrag(bv), acc);
        }
        #pragma unroll
        for (int v = 0; v < 4; ++v)      // fold lo rows (8-15) into hi rows (0-7)
            acc[v] += __shfl_xor(acc[v], 32, 64);
        if (l < 32) {                    // lanes 0-31: rows (l>>4)*4+v, col l&15
            const int r4 = (l >> 4) * 4;
            const int n  = w * 16 + m;
            const float bb = b1[n];
            #pragma unroll
            for (int v = 0; v < 4; ++v) {
                const float h = fmaxf(acc[v] + bb, 0.f);
                const u32 hh = b16(h);
                hbf[0][r4 + v][n] = (u16)hh;
                hbf[1][r4 + v][n] = (u16)b16(h - b16f(hh));
            }
        }
    }
    __syncthreads();

    // ================= layer 2: waves 0-7 own n-tile w ======================
    if (w < 8) {
        f32x4 acc = {0.f, 0.f, 0.f, 0.f};
        const u16* abase = &hbf[pl][rw][kb_l];
        #pragma unroll
        for (int kt = 0; kt < 8; ++kt) {
            const uint4 af = *(const uint4*)(abase + kt * 32);
            const uint4 bv = wsb[(size_t)(W2B_OFF + (kt * 8 + w) * 64 + l)];
            acc = MFMA(asfrag(af), asfrag(bv), acc);
        }
        #pragma unroll
        for (int v = 0; v < 4; ++v) acc[v] += __shfl_xor(acc[v], 32, 64);
        if (l < 32) {
            const int r4 = (l >> 4) * 4;
            const int n  = w * 16 + m;
            const float bb = b2[n];
            #pragma unroll
            for (int v = 0; v < 4; ++v) {
                const float x2 = acc[v] + bb;
                const u32 xh = b16(x2);
                x2bf[0][r4 + v][n] = (u16)xh;
                x2bf[1][r4 + v][n] = (u16)b16(x2 - b16f(xh));
            }
        }
    }
    __syncthreads();

    // ================= score: wave owns 4 n-tiles ===========================
    {
        uint4 sf[4];
        const u16* abase = &x2bf[pl][rw][kb_l];
        #pragma unroll
        for (int kt = 0; kt < 4; ++kt)
            sf[kt] = *(const uint4*)(abase + kt * 32);
        #pragma unroll
        for (int i = 0; i < 4; ++i) {
            const int nt = w * 4 + i;
            if (nt >= 63) break;         // wave 15: 3 tiles (uniform branch)
            f32x4 acc = {0.f, 0.f, 0.f, 0.f};
            #pragma unroll
            for (int kt = 0; kt < 4; ++kt) {
                const uint4 bv = wsb[(size_t)(RB_OFF + (nt * 4 + kt) * 64 + l)];
                acc = MFMA(asfrag(sf[kt]), asfrag(bv), acc);
            }
            #pragma unroll
            for (int v = 0; v < 4; ++v) acc[v] += __shfl_xor(acc[v], 32, 64);
            if (l < 32) {
                const int r4 = (l >> 4) * 4;
                const int n  = nt * 16 + m;
                #pragma unroll
                for (int v = 0; v < 4; ++v)
                    scoreL[(r4 + v) * SCL + n] = acc[v];   // conflict-free
            }
        }
    }
    __syncthreads();

    // ================= wave-local softmax + entropy (waves 0-7) =============
    if (w < 8) {
        float lg[4];
        #pragma unroll
        for (int c = 0; c < 4; ++c)
            lg[c] = scoreL[w * SCL + ridx[c]] - (1.0f - msk[c]) * 1e31f;

        float mx = fmaxf(fmaxf(lg[0], lg[1]), fmaxf(lg[2], lg[3]));
        #pragma unroll
        for (int off = 32; off >= 1; off >>= 1)
            mx = fmaxf(mx, __shfl_xor(mx, off, 64));

        float p[4], S = 0.f, SLa = 0.f;
        #pragma unroll
        for (int c = 0; c < 4; ++c) {
            const float z = lg[c] - mx;
            p[c] = __expf(z);
            S   += p[c];
            SLa += p[c] * z;
        }
        #pragma unroll
        for (int off = 32; off >= 1; off >>= 1) {
            S   += __shfl_xor(S,   off, 64);
            SLa += __shfl_xor(SLa, off, 64);
        }

        const float inv = 1.0f / S;
        #pragma unroll
        for (int c = 0; c < 4; ++c)
            dist_out[(size_t)(b0 + w) * AA + l + 64 * c] = p[c] * inv;
        if (l == 0)
            ent_out[b0 + w] = __logf(S) - SLa * inv;
    }
}

extern "C" void kernel_launch(void* const* d_in, const int* in_sizes, int n_in,
                              void* d_out, int out_size, void* d_ws, size_t ws_size,
                              hipStream_t stream) {
    const int*   e          = (const int*)  d_in[0];
    const int*   q          = (const int*)  d_in[1];
    const float* H          = (const float*)d_in[2];
    const int*   r_space    = (const int*)  d_in[3];
    const float* r_mask     = (const float*)d_in[4];
    const float* entity_emb = (const float*)d_in[5];
    const float* rel_emb    = (const float*)d_in[6];
    const float* W1         = (const float*)d_in[7];
    const float* b1         = (const float*)d_in[8];
    const float* W2         = (const float*)d_in[9];
    const float* b2         = (const float*)d_in[10];

    const int B = in_sizes[0];              // 2048
    float* dist_out = (float*)d_out;                    // [B, 256]
    float* ent_out  = (float*)d_out + (size_t)B * AA;   // [B]
    uint4* wsb      = (uint4*)d_ws;                     // 572 KB packed B-frags

    prep_kernel<<<PREP_T / 256, 256, 0, stream>>>(W1, W2, rel_emb, wsb);
    policy_kernel<<<B / BB, 1024, 0, stream>>>(
        e, q, H, r_space, r_mask, entity_emb, rel_emb,
        b1, b2, wsb, dist_out, ent_out);
}